// Round 3
// baseline (4333.337 us; speedup 1.0000x reference)
//
#include <hip/hip_runtime.h>
#include <stdint.h>

// GRU: SEQ=512, BATCH=64, IN=512, HID=1024. fp32 in/out, bf16 MFMA internally.
//
// Phase 1: gx = x @ W_ih^T + b_ih  (bf16, [512][64][3072] in ws)
// Phase 2: persistent plain-launch kernel, 256 blocks. __launch_bounds__(256,2)
//          caps VGPR at 256 -> 2 blocks/CU capacity -> all 256 blocks
//          co-resident even under uneven dispatch. Block b = (cg=b&63,
//          bh=b>>6): h-cols [16cg,16cg+16) x batch rows [16bh,16bh+16).
//          4 waves split K (256 each); partials reduced via 12KB LDS.
//
//          Round-3 change: h loads and barrier poll loads are INLINE ASM
//          (global_load sc0 sc1 = LLC-coherent, L1/L2 bypass). Round-2
//          counters showed ~340cy per atomic load = LLVM chain-orders
//          monotonic atomic loads, so the intended "issue 16, wait once"
//          never happened. Asm batch: 16 x global_load_dwordx4 off one
//          base VGPR pair with immediate offsets, ONE s_waitcnt vmcnt(0),
//          sched_barrier(0) to stop hipcc hoisting consumers above it.
//          Cross-block h exchange semantics unchanged (same cache bits the
//          atomics emitted; __syncthreads' vmcnt(0) drain orders h stores
//          before the flag store; no cache fences so W_hh/gx stay warm).

#define SEQ    512
#define BATCH  64
#define IN_DIM 512
#define HID    1024
#define G3     3072
#define NBLK   256

typedef __bf16 bf16x8 __attribute__((ext_vector_type(8)));
typedef short  s16x8  __attribute__((ext_vector_type(8)));
typedef float  f32x4  __attribute__((ext_vector_type(4)));
typedef unsigned int u32x4 __attribute__((ext_vector_type(4)));

__device__ __forceinline__ float bf2f(unsigned int u) {
    union { unsigned int i; float f; } c; c.i = u << 16; return c.f;
}
__device__ __forceinline__ unsigned short f2bf(float f) {
    union { float f; unsigned int i; } c; c.f = f;
    unsigned int u = c.i;
    u += 0x7fffu + ((u >> 16) & 1u);   // RNE
    return (unsigned short)(u >> 16);
}

// ---------------------------------------------------------------- converts
__global__ void cvt_f32_bf16(const float* __restrict__ in,
                             unsigned short* __restrict__ out, int n) {
    int i = (blockIdx.x * 256 + threadIdx.x) * 4;
    if (i + 3 < n) {
        float4 v = *(const float4*)(in + i);
        ushort4 o;
        o.x = f2bf(v.x); o.y = f2bf(v.y); o.z = f2bf(v.z); o.w = f2bf(v.w);
        *(ushort4*)(out + i) = o;
    }
}

__global__ void init_state(unsigned int* __restrict__ h0,
                           unsigned int* __restrict__ h1,
                           unsigned int* __restrict__ flags) {
    int i = blockIdx.x * 256 + threadIdx.x;
    if (i < BATCH * HID) { h0[i] = 0u; h1[i] = 0u; }
    if (i < NBLK * 4)    flags[i] = 0u;       // 256 flags, stride 4 u32 (16B)
}

// ---------------------------------------------------------------- gx GEMM
// C[32768][3072] = A[32768][512] @ W[3072][512]^T + b_ih, operands direct
// from global (bf16, L2/L3-resident), 128x128 block tile, 4 waves of 64x64.
__global__ __launch_bounds__(256) void gx_gemm(
    const unsigned short* __restrict__ xb,
    const unsigned short* __restrict__ wb,
    const float* __restrict__ bih,
    unsigned short* __restrict__ gx) {
    const int lane = threadIdx.x & 63;
    const int wv   = threadIdx.x >> 6;
    const int r    = lane & 15;
    const int quad = lane >> 4;
    const int m0 = blockIdx.x * 128 + (wv & 1) * 64;
    const int n0 = blockIdx.y * 128 + (wv >> 1) * 64;

    f32x4 acc[4][4];
#pragma unroll
    for (int a = 0; a < 4; a++)
#pragma unroll
        for (int b = 0; b < 4; b++) acc[a][b] = (f32x4){0.f, 0.f, 0.f, 0.f};

    const unsigned short* ap[4];
    const unsigned short* bp[4];
#pragma unroll
    for (int mi = 0; mi < 4; mi++)
        ap[mi] = xb + (size_t)(m0 + mi * 16 + r) * IN_DIM + quad * 8;
#pragma unroll
    for (int ni = 0; ni < 4; ni++)
        bp[ni] = wb + (size_t)(n0 + ni * 16 + r) * IN_DIM + quad * 8;

#pragma unroll 4
    for (int kk = 0; kk < IN_DIM / 32; kk++) {
        bf16x8 af[4], bf_[4];
#pragma unroll
        for (int mi = 0; mi < 4; mi++)
            af[mi] = __builtin_bit_cast(bf16x8, *(const s16x8*)(ap[mi] + kk * 32));
#pragma unroll
        for (int ni = 0; ni < 4; ni++)
            bf_[ni] = __builtin_bit_cast(bf16x8, *(const s16x8*)(bp[ni] + kk * 32));
#pragma unroll
        for (int mi = 0; mi < 4; mi++)
#pragma unroll
            for (int ni = 0; ni < 4; ni++)
                acc[mi][ni] = __builtin_amdgcn_mfma_f32_16x16x32_bf16(
                    af[mi], bf_[ni], acc[mi][ni], 0, 0, 0);
    }

#pragma unroll
    for (int ni = 0; ni < 4; ni++) {
        const int col = n0 + ni * 16 + r;
        const float bias = bih[col];
#pragma unroll
        for (int mi = 0; mi < 4; mi++)
#pragma unroll
            for (int i = 0; i < 4; i++) {
                const int row = m0 + mi * 16 + quad * 4 + i;  // C/D m89 layout
                gx[(size_t)row * G3 + col] = f2bf(acc[mi][ni][i] + bias);
            }
    }
}

// batched LLC-coherent 16B load: dst <- *(hbase + OFF), L1/L2 bypass
#define HL16(dst, OFF)                                                    \
    asm volatile("global_load_dwordx4 %0, %1, off offset:" OFF " sc0 sc1" \
                 : "=&v"(dst) : "v"(hbase))
#define FL4(dst, OFF)                                                     \
    asm volatile("global_load_dword %0, %1, off offset:" OFF " sc0 sc1"   \
                 : "=&v"(dst) : "v"(fbase))

// ---------------------------------------------------------------- recurrence
// 256 blocks x 256 threads, plain launch (2-blocks/CU capacity, co-resident).
__global__ __launch_bounds__(256, 2) void gru_seq(
    const unsigned short* __restrict__ whb,   // [3072][1024] bf16
    const float* __restrict__ bhh,            // [3072]
    const unsigned short* __restrict__ gxb,   // [512][64][3072] bf16
    unsigned int* __restrict__ h0,            // packed (hi<<16|lo) h, dbuf
    unsigned int* __restrict__ h1,
    unsigned int* __restrict__ flags,         // [256] stride-16B step flags
    float* __restrict__ out) {
    const int lane = threadIdx.x & 63;
    const int wv   = threadIdx.x >> 6;
    const int r    = lane & 15;
    const int quad = lane >> 4;
    const int cg   = blockIdx.x & 63;
    const int bh   = blockIdx.x >> 6;
    const int J0   = cg * 16;     // h-col base
    const int R0   = bh * 16;     // batch row base
    const int k0   = wv * 256;    // this wave's K quarter

    __shared__ float red[4][3][4][64];   // [wave][gate][acc_i][lane], 12 KB
    __shared__ int dead;                 // barrier-timeout latch
    if (threadIdx.x == 0) dead = 0;
    __syncthreads();

    // weight row pointers for this wave's K quarter (L1/L2-warm every step)
    const unsigned short* wr = whb + (size_t)(J0 + r) * HID + k0 + quad * 8;
    const unsigned short* wz = wr + (size_t)HID * HID;
    const unsigned short* wn = wr + (size_t)2 * HID * HID;
    const float bhr = bhh[J0 + r];
    const float bhz = bhh[HID + J0 + r];
    const float bhn = bhh[2 * HID + J0 + r];

    const int    arow = R0 + r;                 // A-frag batch row
    const int    erow = R0 + quad * 4 + wv;     // epilogue row (i = wv)
    const size_t hidx = (size_t)erow * HID + J0 + r;
    const unsigned int* fbase = flags + (size_t)lane * 4;   // poll base

#pragma unroll 1
    for (int t = 0; t < SEQ; t++) {
        const unsigned int* cur = (t & 1) ? h1 : h0;
        unsigned int*       nxt = (t & 1) ? h0 : h1;
        const unsigned short* gxt = gxb + (size_t)t * (BATCH * G3);

        // epilogue operands issued early (LLC gx + old-h), drained with batch
        const float xr = bf2f(gxt[(size_t)erow * G3 + J0 + r]);
        const float xz = bf2f(gxt[(size_t)erow * G3 + HID + J0 + r]);
        const float xn = bf2f(gxt[(size_t)erow * G3 + 2 * HID + J0 + r]);
        const unsigned int hw = __hip_atomic_load(
            cur + hidx, __ATOMIC_RELAXED, __HIP_MEMORY_SCOPE_AGENT);

        // ---- 16 batched coherent h loads: ONE latency exposure ----------
        // per lane: 8 chunks x 32B; chunk kk = bytes [kk*128, kk*128+32)
        const unsigned int* hbase = cur + (size_t)arow * HID + k0 + quad * 8;
        u32x4 q[16];
        HL16(q[0],  "0");    HL16(q[1],  "16");
        HL16(q[2],  "128");  HL16(q[3],  "144");
        HL16(q[4],  "256");  HL16(q[5],  "272");
        HL16(q[6],  "384");  HL16(q[7],  "400");
        HL16(q[8],  "512");  HL16(q[9],  "528");
        HL16(q[10], "640");  HL16(q[11], "656");
        HL16(q[12], "768");  HL16(q[13], "784");
        HL16(q[14], "896");  HL16(q[15], "912");
        asm volatile("s_waitcnt vmcnt(0)" ::: "memory");
        __builtin_amdgcn_sched_barrier(0);   // rule #18: pin consumers below

        f32x4 aR = {0.f, 0.f, 0.f, 0.f};
        f32x4 aZ = {0.f, 0.f, 0.f, 0.f};
        f32x4 aN = {0.f, 0.f, 0.f, 0.f};
#pragma unroll
        for (int kk = 0; kk < 8; kk++) {
            const u32x4 qa = q[2 * kk];
            const u32x4 qb = q[2 * kk + 1];
            u32x4 ahw, alw;
            ahw[0] = __builtin_amdgcn_perm(qa[1], qa[0], 0x07060302u);
            alw[0] = __builtin_amdgcn_perm(qa[1], qa[0], 0x05040100u);
            ahw[1] = __builtin_amdgcn_perm(qa[3], qa[2], 0x07060302u);
            alw[1] = __builtin_amdgcn_perm(qa[3], qa[2], 0x05040100u);
            ahw[2] = __builtin_amdgcn_perm(qb[1], qb[0], 0x07060302u);
            alw[2] = __builtin_amdgcn_perm(qb[1], qb[0], 0x05040100u);
            ahw[3] = __builtin_amdgcn_perm(qb[3], qb[2], 0x07060302u);
            alw[3] = __builtin_amdgcn_perm(qb[3], qb[2], 0x05040100u);
            bf16x8 ah = __builtin_bit_cast(bf16x8, ahw);
            bf16x8 al = __builtin_bit_cast(bf16x8, alw);
            bf16x8 fr = __builtin_bit_cast(bf16x8, *(const s16x8*)(wr + kk * 32));
            bf16x8 fz = __builtin_bit_cast(bf16x8, *(const s16x8*)(wz + kk * 32));
            bf16x8 fn = __builtin_bit_cast(bf16x8, *(const s16x8*)(wn + kk * 32));
            // 3 independent ops between dependent pairs
            aR = __builtin_amdgcn_mfma_f32_16x16x32_bf16(ah, fr, aR, 0, 0, 0);
            aZ = __builtin_amdgcn_mfma_f32_16x16x32_bf16(ah, fz, aZ, 0, 0, 0);
            aN = __builtin_amdgcn_mfma_f32_16x16x32_bf16(ah, fn, aN, 0, 0, 0);
            aR = __builtin_amdgcn_mfma_f32_16x16x32_bf16(al, fr, aR, 0, 0, 0);
            aZ = __builtin_amdgcn_mfma_f32_16x16x32_bf16(al, fz, aZ, 0, 0, 0);
            aN = __builtin_amdgcn_mfma_f32_16x16x32_bf16(al, fn, aN, 0, 0, 0);
        }

        // K-partials -> LDS ([wave][gate][i][lane]: 4B lane stride, no conflicts)
#pragma unroll
        for (int i = 0; i < 4; i++) {
            red[wv][0][i][lane] = aR[i];
            red[wv][1][i][lane] = aZ[i];
            red[wv][2][i][lane] = aN[i];
        }
        __syncthreads();   // (A) partials visible

        // epilogue: wave wv handles accumulator slot i = wv (rows quad*4+wv)
        {
            const float sR = red[0][0][wv][lane] + red[1][0][wv][lane]
                           + red[2][0][wv][lane] + red[3][0][wv][lane];
            const float sZ = red[0][1][wv][lane] + red[1][1][wv][lane]
                           + red[2][1][wv][lane] + red[3][1][wv][lane];
            const float sN = red[0][2][wv][lane] + red[1][2][wv][lane]
                           + red[2][2][wv][lane] + red[3][2][wv][lane];
            const float hold = bf2f(hw >> 16) + bf2f(hw & 0xffffu);
            const float rg = 1.f / (1.f + __expf(-(xr + sR + bhr)));
            const float zg = 1.f / (1.f + __expf(-(xz + sZ + bhz)));
            const float e2 = __expf(2.f * (xn + rg * (sN + bhn)));
            const float ng = 1.f - 2.f / (e2 + 1.f);
            const float hn = (1.f - zg) * ng + zg * hold;
            const unsigned int uhi = f2bf(hn);
            const unsigned int ulo = f2bf(hn - bf2f(uhi));
            __hip_atomic_store(nxt + hidx, (uhi << 16) | ulo,
                               __ATOMIC_RELAXED, __HIP_MEMORY_SCOPE_AGENT);
            out[(size_t)t * (BATCH * HID) + hidx] = hn;
            if (t == SEQ - 1)
                out[(size_t)SEQ * (BATCH * HID) + hidx] = hn;
        }

        if (t != SEQ - 1) {
            // (B): every wave's s_waitcnt vmcnt(0) at this barrier drains the
            // coherent h stores to the LLC -> flag signal is ordered.
            __syncthreads();
            if (threadIdx.x == 0)
                __hip_atomic_store(flags + (size_t)blockIdx.x * 4,
                                   (unsigned int)(t + 1),
                                   __ATOMIC_RELAXED, __HIP_MEMORY_SCOPE_AGENT);
            if (wv == 0 && !dead) {
                const unsigned int tgt = (unsigned int)(t + 1);
                int guard = 0;
                for (;;) {
                    unsigned int f0, f1, f2, f3;     // 4 batched poll loads
                    FL4(f0, "0");
                    FL4(f1, "1024");
                    FL4(f2, "2048");
                    FL4(f3, "3072");
                    asm volatile("s_waitcnt vmcnt(0)" ::: "memory");
                    __builtin_amdgcn_sched_barrier(0);
                    if (__all((f0 >= tgt) && (f1 >= tgt) &&
                              (f2 >= tgt) && (f3 >= tgt)))
                        break;
                    if (++guard > (1 << 20)) {   // ~0.1s: co-residency failsafe
                        if (lane == 0) dead = 1; // report wrong-fast, not hang
                        break;
                    }
                    __builtin_amdgcn_s_sleep(1);
                }
            }
            __syncthreads();   // (C) release all waves into step t+1
        }
    }
}

// ---------------------------------------------------------------- launch
extern "C" void kernel_launch(void* const* d_in, const int* in_sizes, int n_in,
                              void* d_out, int out_size, void* d_ws, size_t ws_size,
                              hipStream_t stream) {
    const float* x   = (const float*)d_in[0];
    const float* Wih = (const float*)d_in[1];
    const float* Whh = (const float*)d_in[2];
    const float* bih = (const float*)d_in[3];
    const float* bhh = (const float*)d_in[4];
    float* out = (float*)d_out;

    char* ws = (char*)d_ws;
    size_t off = 0;
    auto alloc = [&](size_t bytes) {
        char* p = ws + off;
        off += (bytes + 255) & ~(size_t)255;
        return p;
    };
    unsigned int*   flags = (unsigned int*)alloc((size_t)NBLK * 16);
    unsigned int*   h0    = (unsigned int*)alloc((size_t)BATCH * HID * 4);
    unsigned int*   h1    = (unsigned int*)alloc((size_t)BATCH * HID * 4);
    unsigned short* xb    = (unsigned short*)alloc((size_t)SEQ * BATCH * IN_DIM * 2);
    unsigned short* wihb  = (unsigned short*)alloc((size_t)G3 * IN_DIM * 2);
    unsigned short* whhb  = (unsigned short*)alloc((size_t)G3 * HID * 2);
    unsigned short* gxb   = (unsigned short*)alloc((size_t)SEQ * BATCH * G3 * 2);
    (void)ws_size; (void)in_sizes; (void)n_in; (void)out_size;

    init_state<<<(BATCH * HID + 255) / 256, 256, 0, stream>>>(h0, h1, flags);
    cvt_f32_bf16<<<(SEQ * BATCH * IN_DIM / 4) / 256, 256, 0, stream>>>(
        x, xb, SEQ * BATCH * IN_DIM);
    cvt_f32_bf16<<<(G3 * IN_DIM / 4) / 256, 256, 0, stream>>>(Wih, wihb, G3 * IN_DIM);
    cvt_f32_bf16<<<(G3 * HID / 4) / 256, 256, 0, stream>>>(Whh, whhb, G3 * HID);
    gx_gemm<<<dim3(SEQ * BATCH / 128, G3 / 128), 256, 0, stream>>>(
        xb, wihb, bih, gxb);

    gru_seq<<<dim3(NBLK), dim3(256), 0, stream>>>(
        whhb, bhh, gxb, h0, h1, flags, out);
}

// Round 4
// 3104.164 us; speedup vs baseline: 1.3960x; 1.3960x over previous
//
#include <hip/hip_runtime.h>
#include <stdint.h>

// GRU: SEQ=512, BATCH=64, IN=512, HID=1024. fp32 in/out, bf16 MFMA internally.
//
// Phase 1: gx = x @ W_ih^T + b_ih  (bf16, [512][64][3072] in ws)
// Phase 2: persistent plain-launch kernel, 256 blocks. __launch_bounds__(256,2)
//          caps VGPR at 256 -> 2 blocks/CU capacity -> all 256 blocks
//          co-resident even under uneven dispatch. Block b = (cg=b&63,
//          bh=b>>6): h-cols [16cg,16cg+16) x batch rows [16bh,16bh+16).
//          4 waves split K (256 each); partials reduced via 12KB LDS.
//
// Round-4 changes (post-mortem of r3: batched h loads did NOT help ->
// per-load latency was never the bottleneck):
//   1. 24 loop-invariant W_hh fragments HOISTED INTO REGISTERS before the
//      t-loop (96 VGPR). r2/r3 reloaded them from L2 every step (96KB/CU
//      slice > 32KB L1) on the MFMA dependence chain; r3's sched_barrier
//      additionally serialized them behind the h drain (the regression).
//   2. Barrier is GROUP-LOCAL: communication only exists among the 64
//      blocks sharing bh. Flags laid out per group; poller reads its 64
//      flags with ONE dword load/lane (r2/r3: every wave scanned all 4KB
//      -> ~256 coalesced reqs per LLC line per iteration = hot-line
//      contention inflating every LLC interaction).
//   3. out[] HBM store moved after the flag store (off the pre-flag
//      vmcnt(0) drain path; completes under the poll).
//   Cross-block h exchange semantics unchanged: sc0 sc1 loads/stores
//   (LLC-coherent), __syncthreads' vmcnt(0) drain orders h stores before
//   the flag store, no cache fences so W_hh/gx stay warm in cache.

#define SEQ    512
#define BATCH  64
#define IN_DIM 512
#define HID    1024
#define G3     3072
#define NBLK   256

typedef __bf16 bf16x8 __attribute__((ext_vector_type(8)));
typedef short  s16x8  __attribute__((ext_vector_type(8)));
typedef float  f32x4  __attribute__((ext_vector_type(4)));
typedef unsigned int u32x4 __attribute__((ext_vector_type(4)));

__device__ __forceinline__ float bf2f(unsigned int u) {
    union { unsigned int i; float f; } c; c.i = u << 16; return c.f;
}
__device__ __forceinline__ unsigned short f2bf(float f) {
    union { float f; unsigned int i; } c; c.f = f;
    unsigned int u = c.i;
    u += 0x7fffu + ((u >> 16) & 1u);   // RNE
    return (unsigned short)(u >> 16);
}

// ---------------------------------------------------------------- converts
__global__ void cvt_f32_bf16(const float* __restrict__ in,
                             unsigned short* __restrict__ out, int n) {
    int i = (blockIdx.x * 256 + threadIdx.x) * 4;
    if (i + 3 < n) {
        float4 v = *(const float4*)(in + i);
        ushort4 o;
        o.x = f2bf(v.x); o.y = f2bf(v.y); o.z = f2bf(v.z); o.w = f2bf(v.w);
        *(ushort4*)(out + i) = o;
    }
}

__global__ void init_state(unsigned int* __restrict__ h0,
                           unsigned int* __restrict__ h1,
                           unsigned int* __restrict__ flags) {
    int i = blockIdx.x * 256 + threadIdx.x;
    if (i < BATCH * HID) { h0[i] = 0u; h1[i] = 0u; }
    if (i < NBLK * 4)    flags[i] = 0u;   // 4 groups x 64 flags x 16B
}

// ---------------------------------------------------------------- gx GEMM
// C[32768][3072] = A[32768][512] @ W[3072][512]^T + b_ih, operands direct
// from global (bf16, L2/L3-resident), 128x128 block tile, 4 waves of 64x64.
__global__ __launch_bounds__(256) void gx_gemm(
    const unsigned short* __restrict__ xb,
    const unsigned short* __restrict__ wb,
    const float* __restrict__ bih,
    unsigned short* __restrict__ gx) {
    const int lane = threadIdx.x & 63;
    const int wv   = threadIdx.x >> 6;
    const int r    = lane & 15;
    const int quad = lane >> 4;
    const int m0 = blockIdx.x * 128 + (wv & 1) * 64;
    const int n0 = blockIdx.y * 128 + (wv >> 1) * 64;

    f32x4 acc[4][4];
#pragma unroll
    for (int a = 0; a < 4; a++)
#pragma unroll
        for (int b = 0; b < 4; b++) acc[a][b] = (f32x4){0.f, 0.f, 0.f, 0.f};

    const unsigned short* ap[4];
    const unsigned short* bp[4];
#pragma unroll
    for (int mi = 0; mi < 4; mi++)
        ap[mi] = xb + (size_t)(m0 + mi * 16 + r) * IN_DIM + quad * 8;
#pragma unroll
    for (int ni = 0; ni < 4; ni++)
        bp[ni] = wb + (size_t)(n0 + ni * 16 + r) * IN_DIM + quad * 8;

#pragma unroll 4
    for (int kk = 0; kk < IN_DIM / 32; kk++) {
        bf16x8 af[4], bf_[4];
#pragma unroll
        for (int mi = 0; mi < 4; mi++)
            af[mi] = __builtin_bit_cast(bf16x8, *(const s16x8*)(ap[mi] + kk * 32));
#pragma unroll
        for (int ni = 0; ni < 4; ni++)
            bf_[ni] = __builtin_bit_cast(bf16x8, *(const s16x8*)(bp[ni] + kk * 32));
#pragma unroll
        for (int mi = 0; mi < 4; mi++)
#pragma unroll
            for (int ni = 0; ni < 4; ni++)
                acc[mi][ni] = __builtin_amdgcn_mfma_f32_16x16x32_bf16(
                    af[mi], bf_[ni], acc[mi][ni], 0, 0, 0);
    }

#pragma unroll
    for (int ni = 0; ni < 4; ni++) {
        const int col = n0 + ni * 16 + r;
        const float bias = bih[col];
#pragma unroll
        for (int mi = 0; mi < 4; mi++)
#pragma unroll
            for (int i = 0; i < 4; i++) {
                const int row = m0 + mi * 16 + quad * 4 + i;  // C/D m89 layout
                gx[(size_t)row * G3 + col] = f2bf(acc[mi][ni][i] + bias);
            }
    }
}

// batched LLC-coherent loads (L1 bypass, serviced coherently)
#define HL16(dst, OFF)                                                    \
    asm volatile("global_load_dwordx4 %0, %1, off offset:" OFF " sc0 sc1" \
                 : "=&v"(dst) : "v"(hbase))
#define SL4(dst, BASE)                                                    \
    asm volatile("global_load_dword %0, %1, off sc0 sc1"                  \
                 : "=&v"(dst) : "v"(BASE))

// ---------------------------------------------------------------- recurrence
// 256 blocks x 256 threads, plain launch (2-blocks/CU capacity, co-resident).
__global__ __launch_bounds__(256, 2) void gru_seq(
    const unsigned short* __restrict__ whb,   // [3072][1024] bf16
    const float* __restrict__ bhh,            // [3072]
    const unsigned short* __restrict__ gxb,   // [512][64][3072] bf16
    unsigned int* __restrict__ h0,            // packed (hi<<16|lo) h, dbuf
    unsigned int* __restrict__ h1,
    unsigned int* __restrict__ flags,         // [4 groups][64] stride-16B
    float* __restrict__ out) {
    const int lane = threadIdx.x & 63;
    const int wv   = threadIdx.x >> 6;
    const int r    = lane & 15;
    const int quad = lane >> 4;
    const int cg   = blockIdx.x & 63;
    const int bh   = blockIdx.x >> 6;
    const int J0   = cg * 16;     // h-col base
    const int R0   = bh * 16;     // batch row base
    const int k0   = wv * 256;    // this wave's K quarter

    __shared__ float red[4][3][4][64];   // [wave][gate][acc_i][lane], 12 KB
    __shared__ int dead;                 // barrier-timeout latch
    if (threadIdx.x == 0) dead = 0;
    __syncthreads();

    // ---- hoist the 24 loop-invariant W_hh fragments into registers ----
    const unsigned short* wr = whb + (size_t)(J0 + r) * HID + k0 + quad * 8;
    const unsigned short* wzp = wr + (size_t)HID * HID;
    const unsigned short* wnp = wr + (size_t)2 * HID * HID;
    bf16x8 wR[8], wZ[8], wN[8];          // 96 VGPRs, live across the t-loop
#pragma unroll
    for (int kk = 0; kk < 8; kk++) {
        wR[kk] = __builtin_bit_cast(bf16x8, *(const s16x8*)(wr  + kk * 32));
        wZ[kk] = __builtin_bit_cast(bf16x8, *(const s16x8*)(wzp + kk * 32));
        wN[kk] = __builtin_bit_cast(bf16x8, *(const s16x8*)(wnp + kk * 32));
    }
    const float bhr = bhh[J0 + r];
    const float bhz = bhh[HID + J0 + r];
    const float bhn = bhh[2 * HID + J0 + r];

    const int    arow = R0 + r;                 // A-frag batch row
    const int    erow = R0 + quad * 4 + wv;     // epilogue row (i = wv)
    const size_t hidx = (size_t)erow * HID + J0 + r;
    // group-local poll base: this bh-group's 64 flags (16B stride each)
    const unsigned int* fbase = flags + (size_t)(bh * 256 + lane * 4);
    const int myflag = bh * 256 + cg * 4;

#pragma unroll 1
    for (int t = 0; t < SEQ; t++) {
        const unsigned int* cur = (t & 1) ? h1 : h0;
        unsigned int*       nxt = (t & 1) ? h0 : h1;
        const unsigned short* gxt = gxb + (size_t)t * (BATCH * G3);

        // epilogue gx operands issued early (HBM), complete by the vmcnt(0)
        const float xr = bf2f(gxt[(size_t)erow * G3 + J0 + r]);
        const float xz = bf2f(gxt[(size_t)erow * G3 + HID + J0 + r]);
        const float xn = bf2f(gxt[(size_t)erow * G3 + 2 * HID + J0 + r]);

        // ---- batched coherent loads: old-h + 16x16B h-row chunks -------
        const unsigned int* ebase = cur + hidx;
        const unsigned int* hbase = cur + (size_t)arow * HID + k0 + quad * 8;
        unsigned int hw;
        u32x4 q[16];
        SL4(hw, ebase);
        HL16(q[0],  "0");    HL16(q[1],  "16");
        HL16(q[2],  "128");  HL16(q[3],  "144");
        HL16(q[4],  "256");  HL16(q[5],  "272");
        HL16(q[6],  "384");  HL16(q[7],  "400");
        HL16(q[8],  "512");  HL16(q[9],  "528");
        HL16(q[10], "640");  HL16(q[11], "656");
        HL16(q[12], "768");  HL16(q[13], "784");
        HL16(q[14], "896");  HL16(q[15], "912");
        asm volatile("s_waitcnt vmcnt(0)" ::: "memory");
        __builtin_amdgcn_sched_barrier(0);   // rule #18: pin consumers below

        f32x4 aR = {0.f, 0.f, 0.f, 0.f};
        f32x4 aZ = {0.f, 0.f, 0.f, 0.f};
        f32x4 aN = {0.f, 0.f, 0.f, 0.f};
#pragma unroll
        for (int kk = 0; kk < 8; kk++) {
            const u32x4 qa = q[2 * kk];
            const u32x4 qb = q[2 * kk + 1];
            u32x4 ahw, alw;
            ahw[0] = __builtin_amdgcn_perm(qa[1], qa[0], 0x07060302u);
            alw[0] = __builtin_amdgcn_perm(qa[1], qa[0], 0x05040100u);
            ahw[1] = __builtin_amdgcn_perm(qa[3], qa[2], 0x07060302u);
            alw[1] = __builtin_amdgcn_perm(qa[3], qa[2], 0x05040100u);
            ahw[2] = __builtin_amdgcn_perm(qb[1], qb[0], 0x07060302u);
            alw[2] = __builtin_amdgcn_perm(qb[1], qb[0], 0x05040100u);
            ahw[3] = __builtin_amdgcn_perm(qb[3], qb[2], 0x07060302u);
            alw[3] = __builtin_amdgcn_perm(qb[3], qb[2], 0x05040100u);
            bf16x8 ah = __builtin_bit_cast(bf16x8, ahw);
            bf16x8 al = __builtin_bit_cast(bf16x8, alw);
            // pure-register MFMA chain; 3 independent ops between dep pairs
            aR = __builtin_amdgcn_mfma_f32_16x16x32_bf16(ah, wR[kk], aR, 0, 0, 0);
            aZ = __builtin_amdgcn_mfma_f32_16x16x32_bf16(ah, wZ[kk], aZ, 0, 0, 0);
            aN = __builtin_amdgcn_mfma_f32_16x16x32_bf16(ah, wN[kk], aN, 0, 0, 0);
            aR = __builtin_amdgcn_mfma_f32_16x16x32_bf16(al, wR[kk], aR, 0, 0, 0);
            aZ = __builtin_amdgcn_mfma_f32_16x16x32_bf16(al, wZ[kk], aZ, 0, 0, 0);
            aN = __builtin_amdgcn_mfma_f32_16x16x32_bf16(al, wN[kk], aN, 0, 0, 0);
        }

        // K-partials -> LDS ([wave][gate][i][lane]: 4B lane stride, no conflicts)
#pragma unroll
        for (int i = 0; i < 4; i++) {
            red[wv][0][i][lane] = aR[i];
            red[wv][1][i][lane] = aZ[i];
            red[wv][2][i][lane] = aN[i];
        }
        __syncthreads();   // (A) partials visible

        // epilogue: wave wv handles accumulator slot i = wv (rows quad*4+wv)
        const float sR = red[0][0][wv][lane] + red[1][0][wv][lane]
                       + red[2][0][wv][lane] + red[3][0][wv][lane];
        const float sZ = red[0][1][wv][lane] + red[1][1][wv][lane]
                       + red[2][1][wv][lane] + red[3][1][wv][lane];
        const float sN = red[0][2][wv][lane] + red[1][2][wv][lane]
                       + red[2][2][wv][lane] + red[3][2][wv][lane];
        const float hold = bf2f(hw >> 16) + bf2f(hw & 0xffffu);
        const float rg = 1.f / (1.f + __expf(-(xr + sR + bhr)));
        const float zg = 1.f / (1.f + __expf(-(xz + sZ + bhz)));
        const float e2 = __expf(2.f * (xn + rg * (sN + bhn)));
        const float ng = 1.f - 2.f / (e2 + 1.f);
        const float hn = (1.f - zg) * ng + zg * hold;
        const unsigned int uhi = f2bf(hn);
        const unsigned int ulo = f2bf(hn - bf2f(uhi));
        __hip_atomic_store(nxt + hidx, (uhi << 16) | ulo,
                           __ATOMIC_RELAXED, __HIP_MEMORY_SCOPE_AGENT);

        if (t != SEQ - 1) {
            // (B): every wave's s_waitcnt vmcnt(0) at this barrier drains the
            // coherent h store to the LLC -> flag signal is ordered.
            __syncthreads();
            if (threadIdx.x == 0)
                __hip_atomic_store(flags + myflag, (unsigned int)(t + 1),
                                   __ATOMIC_RELAXED, __HIP_MEMORY_SCOPE_AGENT);
            // out store off the drain path: completes under the poll
            out[(size_t)t * (BATCH * HID) + hidx] = hn;
            if (wv == 0 && !dead) {
                const unsigned int tgt = (unsigned int)(t + 1);
                int guard = 0;
                for (;;) {
                    unsigned int f0;          // ONE group-local poll load
                    SL4(f0, fbase);
                    asm volatile("s_waitcnt vmcnt(0)" ::: "memory");
                    __builtin_amdgcn_sched_barrier(0);
                    if (__all(f0 >= tgt)) break;
                    if (++guard > (1 << 20)) {   // ~0.3s: co-residency failsafe
                        if (lane == 0) dead = 1; // report wrong-fast, not hang
                        break;
                    }
                    __builtin_amdgcn_s_sleep(1);
                }
            }
            __syncthreads();   // (C) release all waves into step t+1
        } else {
            out[(size_t)t * (BATCH * HID) + hidx] = hn;
            out[(size_t)SEQ * (BATCH * HID) + hidx] = hn;
        }
    }
}

// ---------------------------------------------------------------- launch
extern "C" void kernel_launch(void* const* d_in, const int* in_sizes, int n_in,
                              void* d_out, int out_size, void* d_ws, size_t ws_size,
                              hipStream_t stream) {
    const float* x   = (const float*)d_in[0];
    const float* Wih = (const float*)d_in[1];
    const float* Whh = (const float*)d_in[2];
    const float* bih = (const float*)d_in[3];
    const float* bhh = (const float*)d_in[4];
    float* out = (float*)d_out;

    char* ws = (char*)d_ws;
    size_t off = 0;
    auto alloc = [&](size_t bytes) {
        char* p = ws + off;
        off += (bytes + 255) & ~(size_t)255;
        return p;
    };
    unsigned int*   flags = (unsigned int*)alloc((size_t)NBLK * 16);
    unsigned int*   h0    = (unsigned int*)alloc((size_t)BATCH * HID * 4);
    unsigned int*   h1    = (unsigned int*)alloc((size_t)BATCH * HID * 4);
    unsigned short* xb    = (unsigned short*)alloc((size_t)SEQ * BATCH * IN_DIM * 2);
    unsigned short* wihb  = (unsigned short*)alloc((size_t)G3 * IN_DIM * 2);
    unsigned short* whhb  = (unsigned short*)alloc((size_t)G3 * HID * 2);
    unsigned short* gxb   = (unsigned short*)alloc((size_t)SEQ * BATCH * G3 * 2);
    (void)ws_size; (void)in_sizes; (void)n_in; (void)out_size;

    init_state<<<(BATCH * HID + 255) / 256, 256, 0, stream>>>(h0, h1, flags);
    cvt_f32_bf16<<<(SEQ * BATCH * IN_DIM / 4) / 256, 256, 0, stream>>>(
        x, xb, SEQ * BATCH * IN_DIM);
    cvt_f32_bf16<<<(G3 * IN_DIM / 4) / 256, 256, 0, stream>>>(Wih, wihb, G3 * IN_DIM);
    cvt_f32_bf16<<<(G3 * HID / 4) / 256, 256, 0, stream>>>(Whh, whhb, G3 * HID);
    gx_gemm<<<dim3(SEQ * BATCH / 128, G3 / 128), 256, 0, stream>>>(
        xb, wihb, bih, gxb);

    gru_seq<<<dim3(NBLK), dim3(256), 0, stream>>>(
        whhb, bhh, gxb, h0, h1, flags, out);
}